// Round 6
// baseline (388.756 us; speedup 1.0000x reference)
//
#include <hip/hip_runtime.h>

// ---------------------------------------------------------------------------
// DoshaGAT: 3-layer GAT. R6 = R5 with the B-staging bug fixed:
//  R5 staged 4x uint4 at stride 16 SHORTS (uint4 = 8 shorts) -> half the LDS
//  panel was uninitialized -> NaN cascade. Now 8x uint4 at stride 8 shorts.
//  - Persistent-B MFMA GEMM: B panel (32KB) staged to LDS once per block;
//    A fragments streamed from global with 1-step prefetch; single barrier.
//  - Aggregate: bf16 unpack via dword shift/and; 8-deep edge pipeline.
// h layout: bf16, head-block-permuted (phys p = c16*CF+cf <-> logical
// L = cf*16+c16 within each head block); consumers re-index by the fixed perm.
// ---------------------------------------------------------------------------

#define WSZ 64

typedef short short8 __attribute__((ext_vector_type(8)));
typedef float float4v __attribute__((ext_vector_type(4)));

__device__ inline unsigned short f2bf(float f) {  // RNE f32->bf16
  unsigned u = __float_as_uint(f);
  u += 0x7FFFu + ((u >> 16) & 1u);
  return (unsigned short)(u >> 16);
}

// ---------------- CSR build ----------------

__global__ __launch_bounds__(256) void hist_kernel(const int* __restrict__ dst, int E,
                                                   int* __restrict__ deg) {
  int e = blockIdx.x * 256 + threadIdx.x;
  if (e < E) atomicAdd(&deg[dst[e]], 1);
}

__global__ __launch_bounds__(256) void block_sums_kernel(const int* __restrict__ deg, int n,
                                                         int* __restrict__ bsum) {
  __shared__ int sh[256];
  int t = threadIdx.x;
  int base = blockIdx.x * 1024 + t * 4;
  int v = 0;
#pragma unroll
  for (int j = 0; j < 4; ++j) {
    int idx = base + j;
    if (idx < n) v += deg[idx];
  }
  sh[t] = v;
  __syncthreads();
  for (int off = 128; off >= 1; off >>= 1) {
    if (t < off) sh[t] += sh[t + off];
    __syncthreads();
  }
  if (t == 0) bsum[blockIdx.x] = sh[0];
}

__global__ void tiny_scan_kernel(int* bsum, int nb) {
  if (threadIdx.x == 0 && blockIdx.x == 0) {
    int run = 0;
    for (int i = 0; i < nb; ++i) {
      int v = bsum[i];
      bsum[i] = run;
      run += v;
    }
  }
}

__global__ __launch_bounds__(256) void scan_write_kernel(const int* __restrict__ deg, int n,
                                                         const int* __restrict__ bbase,
                                                         int* __restrict__ row_start,
                                                         int* __restrict__ cursor) {
  __shared__ int sh[256];
  int t = threadIdx.x;
  int base = blockIdx.x * 1024 + t * 4;
  int v[4];
  int s = 0;
#pragma unroll
  for (int j = 0; j < 4; ++j) {
    int idx = base + j;
    v[j] = (idx < n) ? deg[idx] : 0;
    s += v[j];
  }
  sh[t] = s;
  __syncthreads();
  for (int off = 1; off < 256; off <<= 1) {
    int x = (t >= off) ? sh[t - off] : 0;
    __syncthreads();
    sh[t] += x;
    __syncthreads();
  }
  int excl = sh[t] - s + bbase[blockIdx.x];
#pragma unroll
  for (int j = 0; j < 4; ++j) {
    int idx = base + j;
    if (idx < n) {
      row_start[idx] = excl;
      cursor[idx] = excl;
    }
    excl += v[j];
  }
  if (blockIdx.x == gridDim.x - 1 && t == 255) row_start[n] = excl;  // == E
}

__global__ __launch_bounds__(256) void scatter_kernel(const int* __restrict__ src,
                                                      const int* __restrict__ dst, int E,
                                                      int* __restrict__ cursor,
                                                      int* __restrict__ csr_src) {
  int e = blockIdx.x * 256 + threadIdx.x;
  if (e < E) {
    int d = dst[e];
    int p = atomicAdd(&cursor[d], 1);
    csr_src[p] = src[e];
  }
}

// ---------------- conversions ----------------

__global__ __launch_bounds__(256) void conv_bf16x4(const float* __restrict__ in,
                                                   unsigned short* __restrict__ out, int n4) {
  int i = blockIdx.x * 256 + threadIdx.x;
  if (i < n4) {
    float4 v = ((const float4*)in)[i];
    ushort4 u;
    u.x = f2bf(v.x); u.y = f2bf(v.y); u.z = f2bf(v.z); u.w = f2bf(v.w);
    ((ushort4*)out)[i] = u;
  }
}

// W1 [128][256] -> W1t [256][128] bf16
__global__ __launch_bounds__(256) void conv_w1t_kernel(const float* __restrict__ W1,
                                                       unsigned short* __restrict__ W1t) {
  int idx = blockIdx.x * 256 + threadIdx.x;  // 32768
  int n = idx >> 7, k = idx & 127;
  W1t[idx] = f2bf(W1[k * 256 + n]);
}

// W2 [256][128] -> W2t [128][256] bf16, K rows permuted to layer-1 phys layout
__global__ __launch_bounds__(256) void conv_w2t_kernel(const float* __restrict__ W2,
                                                       unsigned short* __restrict__ W2t) {
  int idx = blockIdx.x * 256 + threadIdx.x;  // 32768
  int n = idx >> 8, p = idx & 255;
  int kl = (p & ~63) | ((p & 3) << 4) | ((p >> 2) & 15);
  W2t[idx] = f2bf(W2[kl * 128 + n]);
}

// ---------------- persistent-B MFMA GEMM + fused attn-coeff epilogue --------
// C[M,NTOT] = A[M,K] @ B[K,NTOT], bf16 in / bf16(phys-perm) out.
// Grid: (ceil(M/128), 2 col-groups). Block: 256 thr / 4 waves.
// Each block: stage its COLS=NTOT/2 B-panel (32KB) to LDS once; each wave
// computes 32 rows x COLS via 2x CFW MFMA accs, A-frags direct from global.

template <int K, int NTOT>
__global__ __launch_bounds__(256) void gemm_mfma2(
    const unsigned short* __restrict__ A,   // [M][K] bf16
    const unsigned short* __restrict__ Bt,  // [NTOT][K] bf16 (pre-transposed)
    const float* __restrict__ a_s, const float* __restrict__ a_d,  // [NTOT] logical
    unsigned short* __restrict__ hout,      // [M][NTOT] bf16 physical layout
    float* __restrict__ als, float* __restrict__ ald,  // [M][4]
    int M) {
  constexpr int COLS = NTOT / 2;      // cols per block (128 / 64)
  constexpr int CFW = COLS / 16;      // col-frags per wave (8 / 4)
  constexpr int HLOG = NTOT / 4;      // logical cols per head (64 / 32)
  constexpr int CFH = HLOG / 16;      // col-frags per head (4 / 2)
  constexpr int VPT = NTOT / 64;      // phys pack width (4 / 2)
  constexpr int KS = K / 32;          // k-steps (4 / 8)
  __shared__ __align__(16) unsigned short Bs[COLS][K + 8];

  const int t = threadIdx.x;
  const int w = t >> 6;
  const int lane = t & 63;
  const int c16 = lane & 15;
  const int q = lane >> 4;
  const int gcol = blockIdx.y;
  const int bm = blockIdx.x * 128;

  // ---- stage B panel (COLS x K = 32 KB) once: 128 B (8x uint4) per thread --
  {
    constexpr int TPR = K / 64;            // threads per B row (2 / 4)
    int nloc = t / TPR;                    // 0..COLS-1
    int part = (t % TPR) * 64;             // shorts offset
    const unsigned short* srcp = Bt + (size_t)(gcol * COLS + nloc) * K + part;
#pragma unroll
    for (int j = 0; j < 8; ++j) {
      uint4 v = *(const uint4*)(srcp + j * 8);   // 8 shorts = 16 B
      *(uint4*)&Bs[nloc][part + j * 8] = v;
    }
  }
  // A-frag prefetch for k-step 0 (before the barrier: independent of LDS)
  int arow[2];
  arow[0] = min(bm + w * 32 + c16, M - 1);
  arow[1] = min(bm + w * 32 + 16 + c16, M - 1);
  short8 afr[2];
#pragma unroll
  for (int rf = 0; rf < 2; ++rf)
    afr[rf] = *(const short8*)(A + (size_t)arow[rf] * K + q * 8);
  __syncthreads();

  float4v acc[2][CFW];
#pragma unroll
  for (int rf = 0; rf < 2; ++rf)
#pragma unroll
    for (int cf = 0; cf < CFW; ++cf) acc[rf][cf] = float4v{0.f, 0.f, 0.f, 0.f};

#pragma unroll
  for (int ks = 0; ks < KS; ++ks) {
    short8 anx[2];
    if (ks + 1 < KS) {
#pragma unroll
      for (int rf = 0; rf < 2; ++rf)
        anx[rf] = *(const short8*)(A + (size_t)arow[rf] * K + (ks + 1) * 32 + q * 8);
    }
#pragma unroll
    for (int cf = 0; cf < CFW; ++cf) {
      short8 bfrag = *(const short8*)&Bs[cf * 16 + c16][ks * 32 + q * 8];
#pragma unroll
      for (int rf = 0; rf < 2; ++rf)
        acc[rf][cf] =
            __builtin_amdgcn_mfma_f32_16x16x32_bf16(afr[rf], bfrag, acc[rf][cf], 0, 0, 0);
    }
    if (ks + 1 < KS) {
      afr[0] = anx[0];
      afr[1] = anx[1];
    }
  }

  // ---- epilogue: phys-perm bf16 store + als/ald (2 heads per wave) ----
  float sasv[CFW], sadv[CFW];
#pragma unroll
  for (int cf = 0; cf < CFW; ++cf) {
    int L = gcol * COLS + cf * 16 + c16;
    sasv[cf] = a_s[L];
    sadv[cf] = a_d[L];
  }
#pragma unroll
  for (int rf = 0; rf < 2; ++rf) {
#pragma unroll
    for (int r = 0; r < 4; ++r) {
      int n = bm + w * 32 + rf * 16 + q * 4 + r;
      float ps[2] = {0.f, 0.f}, pd[2] = {0.f, 0.f};
      unsigned short us[CFW];
#pragma unroll
      for (int cf = 0; cf < CFW; ++cf) {
        float v = acc[rf][cf][r];
        us[cf] = f2bf(v);
        ps[cf / CFH] += v * sasv[cf];
        pd[cf / CFH] += v * sadv[cf];
      }
#pragma unroll
      for (int off = 1; off <= 8; off <<= 1) {
#pragma unroll
        for (int hl = 0; hl < 2; ++hl) {
          ps[hl] += __shfl_xor(ps[hl], off, 16);
          pd[hl] += __shfl_xor(pd[hl], off, 16);
        }
      }
      if (n < M) {
#pragma unroll
        for (int hl = 0; hl < 2; ++hl) {
          int head = gcol * 2 + hl;
          unsigned short* dst = hout + (size_t)n * NTOT + head * HLOG + c16 * VPT;
          if constexpr (VPT == 4) {
            ushort4 u;
            u.x = us[hl * 4 + 0]; u.y = us[hl * 4 + 1];
            u.z = us[hl * 4 + 2]; u.w = us[hl * 4 + 3];
            *(ushort4*)dst = u;
          } else {
            ushort2 u;
            u.x = us[hl * 2 + 0]; u.y = us[hl * 2 + 1];
            *(ushort2*)dst = u;
          }
          if (c16 == 0) {
            als[(size_t)n * 4 + head] = ps[hl];
            ald[(size_t)n * 4 + head] = pd[hl];
          }
        }
      }
    }
  }
}

// ---------------- GAT aggregation + bias + BN + ELU (+ fused layer-3 prep) --

template <int D, bool FUSEL3>
__global__ __launch_bounds__(256) void gat_aggregate(
    const unsigned short* __restrict__ h_bf, const float* __restrict__ als,
    const float* __restrict__ ald, const int* __restrict__ row_start,
    const int* __restrict__ csr_src, const float* __restrict__ bias,
    const float* __restrict__ gamma, const float* __restrict__ beta,
    const float* __restrict__ bmean, const float* __restrict__ bvar,
    unsigned short* __restrict__ obf,  // D==256 output
    const float* __restrict__ W3, const float* __restrict__ a3s,
    const float* __restrict__ a3d, float4* __restrict__ h3p,
    float* __restrict__ ald3,  // FUSEL3 outputs
    int n_nodes) {
  constexpr int VPT = D / WSZ;
  constexpr int H = 4;
  __shared__ float w3s[384];
  __shared__ float sa3[6];
  if constexpr (FUSEL3) {
    for (int i = threadIdx.x; i < 384; i += 256) w3s[i] = W3[i];
    if (threadIdx.x < 3) {
      sa3[threadIdx.x] = a3s[threadIdx.x];
      sa3[3 + threadIdx.x] = a3d[threadIdx.x];
    }
    __syncthreads();
  }
  int wid = threadIdx.x >> 6, lane = threadIdx.x & 63;
  int n = blockIdx.x * 4 + wid;
  if (n >= n_nodes) return;
  int c = lane * VPT;  // physical col base
  int hd = lane >> 4;  // head
  float aldv = ald[(size_t)n * H + hd];
  int row = row_start[n], end = row_start[n + 1];
  float acc[VPT] = {};
  float ssum = 0.f;
  int i = row;

#define EDGE_BLOCK(B)                                                          \
  for (; i + (B) - 1 < end; i += (B)) {                                        \
    int s[B];                                                                  \
    float e[B];                                                                \
    _Pragma("unroll") for (int j = 0; j < (B); ++j) s[j] = csr_src[i + j];     \
    _Pragma("unroll") for (int j = 0; j < (B); ++j) e[j] =                     \
        als[(size_t)s[j] * H + hd] + aldv;                                     \
    if constexpr (VPT == 4) {                                                  \
      uint2 u[B];                                                              \
      _Pragma("unroll") for (int j = 0; j < (B); ++j) u[j] =                   \
          *(const uint2*)(h_bf + (size_t)s[j] * D + c);                        \
      _Pragma("unroll") for (int j = 0; j < (B); ++j) {                        \
        float ee = e[j];                                                       \
        ee = (ee > 0.f) ? ee : 0.2f * ee;                                      \
        float ex = __expf(ee);                                                 \
        ssum += ex;                                                            \
        acc[0] += ex * __uint_as_float(u[j].x << 16);                          \
        acc[1] += ex * __uint_as_float(u[j].x & 0xFFFF0000u);                  \
        acc[2] += ex * __uint_as_float(u[j].y << 16);                          \
        acc[3] += ex * __uint_as_float(u[j].y & 0xFFFF0000u);                  \
      }                                                                        \
    } else {                                                                   \
      unsigned u[B];                                                           \
      _Pragma("unroll") for (int j = 0; j < (B); ++j) u[j] =                   \
          *(const unsigned*)(h_bf + (size_t)s[j] * D + c);                     \
      _Pragma("unroll") for (int j = 0; j < (B); ++j) {                        \
        float ee = e[j];                                                       \
        ee = (ee > 0.f) ? ee : 0.2f * ee;                                      \
        float ex = __expf(ee);                                                 \
        ssum += ex;                                                            \
        acc[0] += ex * __uint_as_float(u[j] << 16);                            \
        acc[1] += ex * __uint_as_float(u[j] & 0xFFFF0000u);                    \
      }                                                                        \
    }                                                                          \
  }

  EDGE_BLOCK(8)
  EDGE_BLOCK(4)
  EDGE_BLOCK(1)
#undef EDGE_BLOCK

  float inv = 1.f / (ssum + 1e-16f);
#pragma unroll
  for (int j = 0; j < VPT; ++j) {
    int cl = hd * (VPT * 16) + j * 16 + (lane & 15);  // logical col
    float o = acc[j] * inv + bias[cl];
    o = (o - bmean[cl]) * rsqrtf(bvar[cl] + 1e-5f) * gamma[cl] + beta[cl];
    o = (o > 0.f) ? o : (__expf(o) - 1.f);  // ELU
    acc[j] = o;
  }
  if constexpr (!FUSEL3) {
    ushort4 u;
    u.x = f2bf(acc[0]); u.y = f2bf(acc[1]); u.z = f2bf(acc[2]); u.w = f2bf(acc[3]);
    *(ushort4*)(obf + (size_t)n * D + c) = u;
  } else {
    // fused l3_prep: o2 row lives in acc[0..1] (phys cols c, c+1).
    int k0l = hd * 32 + (lane & 15);  // logical k of acc[0]
    int k1l = k0l + 16;               // logical k of acc[1]
    float p0 = acc[0] * w3s[k0l * 3 + 0] + acc[1] * w3s[k1l * 3 + 0];
    float p1 = acc[0] * w3s[k0l * 3 + 1] + acc[1] * w3s[k1l * 3 + 1];
    float p2 = acc[0] * w3s[k0l * 3 + 2] + acc[1] * w3s[k1l * 3 + 2];
#pragma unroll
    for (int off = 32; off >= 1; off >>= 1) {
      p0 += __shfl_xor(p0, off, 64);
      p1 += __shfl_xor(p1, off, 64);
      p2 += __shfl_xor(p2, off, 64);
    }
    if (lane == 0) {
      float als3 = p0 * sa3[0] + p1 * sa3[1] + p2 * sa3[2];
      float ad3 = p0 * sa3[3] + p1 * sa3[4] + p2 * sa3[5];
      h3p[n] = make_float4(p0, p1, p2, als3);
      ald3[n] = ad3;
    }
  }
}

// ---------------- layer 3 aggregation + log_softmax -------------------------

__global__ __launch_bounds__(256) void l3_agg_kernel(const float4* __restrict__ h3p,
                                                     const float* __restrict__ ald3,
                                                     const int* __restrict__ row_start,
                                                     const int* __restrict__ csr_src,
                                                     const float* __restrict__ b3,
                                                     float* __restrict__ out, int n_nodes) {
  int wid = threadIdx.x >> 6, lane = threadIdx.x & 63;
  int n = blockIdx.x * 4 + wid;
  if (n >= n_nodes) return;
  float aldv = ald3[n];
  int row = row_start[n], end = row_start[n + 1];
  float a0 = 0.f, a1 = 0.f, a2 = 0.f, ss = 0.f;
  for (int i = row + lane; i < end; i += 64) {
    int s = csr_src[i];
    float4 hv = h3p[s];
    float e = hv.w + aldv;
    e = (e > 0.f) ? e : 0.2f * e;
    float ex = __expf(e);
    ss += ex;
    a0 += ex * hv.x;
    a1 += ex * hv.y;
    a2 += ex * hv.z;
  }
#pragma unroll
  for (int off = 32; off >= 1; off >>= 1) {
    a0 += __shfl_xor(a0, off, 64);
    a1 += __shfl_xor(a1, off, 64);
    a2 += __shfl_xor(a2, off, 64);
    ss += __shfl_xor(ss, off, 64);
  }
  if (lane == 0) {
    float inv = 1.f / (ss + 1e-16f);
    float o0 = a0 * inv + b3[0];
    float o1 = a1 * inv + b3[1];
    float o2 = a2 * inv + b3[2];
    float m = fmaxf(o0, fmaxf(o1, o2));
    float lse = m + logf(expf(o0 - m) + expf(o1 - m) + expf(o2 - m));
    out[n * 3 + 0] = o0 - lse;
    out[n * 3 + 1] = o1 - lse;
    out[n * 3 + 2] = o2 - lse;
  }
}

// ---------------------------------------------------------------------------

extern "C" void kernel_launch(void* const* d_in, const int* in_sizes, int n_in,
                              void* d_out, int out_size, void* d_ws, size_t ws_size,
                              hipStream_t stream) {
  const float* x   = (const float*)d_in[0];
  const int*   ei  = (const int*)d_in[1];
  const float* W1  = (const float*)d_in[2];
  const float* a1s = (const float*)d_in[3];
  const float* a1d = (const float*)d_in[4];
  const float* b1  = (const float*)d_in[5];
  const float* g1v = (const float*)d_in[6];
  const float* be1 = (const float*)d_in[7];
  const float* m1  = (const float*)d_in[8];
  const float* v1  = (const float*)d_in[9];
  const float* W2  = (const float*)d_in[10];
  const float* a2s = (const float*)d_in[11];
  const float* a2d = (const float*)d_in[12];
  const float* b2  = (const float*)d_in[13];
  const float* g2v = (const float*)d_in[14];
  const float* be2 = (const float*)d_in[15];
  const float* m2  = (const float*)d_in[16];
  const float* v2  = (const float*)d_in[17];
  const float* W3  = (const float*)d_in[18];
  const float* a3s = (const float*)d_in[19];
  const float* a3d = (const float*)d_in[20];
  const float* b3  = (const float*)d_in[21];
  float* out = (float*)d_out;

  const int N = in_sizes[0] / 128;  // 50000
  const int E = in_sizes[1] / 2;    // 850000
  const int* srcv = ei;
  const int* dstv = ei + E;

  // workspace carve-up (~90 MB)
  float* wsf  = (float*)d_ws;
  float* als1 = wsf;                  // N*4
  float* ald1 = als1 + (size_t)N * 4;
  float* als2 = ald1 + (size_t)N * 4;
  float* ald2 = als2 + (size_t)N * 4;
  float* h3p  = ald2 + (size_t)N * 4;  // N*4 (float4 rows)
  float* ald3 = h3p + (size_t)N * 4;   // N
  unsigned short* x_bf  = (unsigned short*)(ald3 + N);  // N*128
  unsigned short* h_bf1 = x_bf + (size_t)N * 128;       // N*256
  unsigned short* o1_bf = h_bf1 + (size_t)N * 256;      // N*256
  unsigned short* h_bf2 = o1_bf + (size_t)N * 256;      // N*128
  unsigned short* W1t   = h_bf2 + (size_t)N * 128;      // 256*128
  unsigned short* W2t   = W1t + 256 * 128;              // 128*256
  int* deg       = (int*)(W2t + 128 * 256);  // N
  int* row_start = deg + N;                  // N+1
  int* cursor    = row_start + (N + 1);      // N+1
  int* csr_src   = cursor + (N + 1);         // E
  int* bsum      = csr_src + E;              // 1024

  const int eb = (E + 255) / 256;
  const int nb = (N + 1023) / 1024;
  const int nodes4 = (N + 3) / 4;
  const dim3 gemm_grid((N + 127) / 128, 2);

  // conversions
  conv_bf16x4<<<(N * 128 / 4 + 255) / 256, 256, 0, stream>>>(x, x_bf, N * 128 / 4);
  conv_w1t_kernel<<<128, 256, 0, stream>>>(W1, W1t);
  conv_w2t_kernel<<<128, 256, 0, stream>>>(W2, W2t);

  // CSR build (shared by all 3 layers)
  hipMemsetAsync(deg, 0, (size_t)N * sizeof(int), stream);
  hist_kernel<<<eb, 256, 0, stream>>>(dstv, E, deg);
  block_sums_kernel<<<nb, 256, 0, stream>>>(deg, N, bsum);
  tiny_scan_kernel<<<1, 64, 0, stream>>>(bsum, nb);
  scan_write_kernel<<<nb, 256, 0, stream>>>(deg, N, bsum, row_start, cursor);
  scatter_kernel<<<eb, 256, 0, stream>>>(srcv, dstv, E, cursor, csr_src);

  // layer 1
  gemm_mfma2<128, 256><<<gemm_grid, 256, 0, stream>>>(x_bf, W1t, a1s, a1d, h_bf1, als1,
                                                      ald1, N);
  gat_aggregate<256, false><<<nodes4, 256, 0, stream>>>(
      h_bf1, als1, ald1, row_start, csr_src, b1, g1v, be1, m1, v1, o1_bf, nullptr, nullptr,
      nullptr, nullptr, nullptr, N);
  // layer 2
  gemm_mfma2<256, 128><<<gemm_grid, 256, 0, stream>>>(o1_bf, W2t, a2s, a2d, h_bf2, als2,
                                                      ald2, N);
  gat_aggregate<128, true><<<nodes4, 256, 0, stream>>>(
      h_bf2, als2, ald2, row_start, csr_src, b2, g2v, be2, m2, v2, nullptr, W3, a3s, a3d,
      (float4*)h3p, ald3, N);
  // layer 3 + log_softmax
  l3_agg_kernel<<<nodes4, 256, 0, stream>>>((const float4*)h3p, ald3, row_start, csr_src,
                                            b3, out, N);
}

// Round 7
// 383.577 us; speedup vs baseline: 1.0135x; 1.0135x over previous
//
#include <hip/hip_runtime.h>

// ---------------------------------------------------------------------------
// DoshaGAT: 3-layer GAT. R7:
//  - GEMM: ALL A-fragments prefetched upfront (single latency exposure);
//    gemm1 reads f32 x directly (in-register cvt) -> conv_bf16x4 eliminated.
//  - tiny_scan (serial, ~49 dependent HBM round-trips) -> one-wave shuffle scan.
//  - weight transposes merged into one dispatch.
// h layout: bf16, head-block-permuted (phys p = c16*VPT+cf <-> logical
// L = cf*16+c16 within each head block); consumers re-index by the fixed perm.
// ---------------------------------------------------------------------------

#define WSZ 64

typedef short short8 __attribute__((ext_vector_type(8)));
typedef float float4v __attribute__((ext_vector_type(4)));

__device__ inline unsigned short f2bf(float f) {  // RNE f32->bf16
  unsigned u = __float_as_uint(f);
  u += 0x7FFFu + ((u >> 16) & 1u);
  return (unsigned short)(u >> 16);
}

// ---------------- CSR build ----------------

__global__ __launch_bounds__(256) void hist_kernel(const int* __restrict__ dst, int E,
                                                   int* __restrict__ deg) {
  int e = blockIdx.x * 256 + threadIdx.x;
  if (e < E) atomicAdd(&deg[dst[e]], 1);
}

__global__ __launch_bounds__(256) void block_sums_kernel(const int* __restrict__ deg, int n,
                                                         int* __restrict__ bsum) {
  __shared__ int sh[256];
  int t = threadIdx.x;
  int base = blockIdx.x * 1024 + t * 4;
  int v = 0;
#pragma unroll
  for (int j = 0; j < 4; ++j) {
    int idx = base + j;
    if (idx < n) v += deg[idx];
  }
  sh[t] = v;
  __syncthreads();
  for (int off = 128; off >= 1; off >>= 1) {
    if (t < off) sh[t] += sh[t + off];
    __syncthreads();
  }
  if (t == 0) bsum[blockIdx.x] = sh[0];
}

// one wave, nb <= 64: exclusive scan of block sums via shuffles
__global__ void scan_blocks_kernel(int* bsum, int nb) {
  int lane = threadIdx.x & 63;
  int orig = (lane < nb) ? bsum[lane] : 0;
  int v = orig;
#pragma unroll
  for (int off = 1; off < 64; off <<= 1) {
    int o = __shfl_up(v, off, 64);
    if (lane >= off) v += o;
  }
  if (lane < nb) bsum[lane] = v - orig;  // exclusive
}

__global__ __launch_bounds__(256) void scan_write_kernel(const int* __restrict__ deg, int n,
                                                         const int* __restrict__ bbase,
                                                         int* __restrict__ row_start,
                                                         int* __restrict__ cursor) {
  __shared__ int sh[256];
  int t = threadIdx.x;
  int base = blockIdx.x * 1024 + t * 4;
  int v[4];
  int s = 0;
#pragma unroll
  for (int j = 0; j < 4; ++j) {
    int idx = base + j;
    v[j] = (idx < n) ? deg[idx] : 0;
    s += v[j];
  }
  sh[t] = s;
  __syncthreads();
  for (int off = 1; off < 256; off <<= 1) {
    int x = (t >= off) ? sh[t - off] : 0;
    __syncthreads();
    sh[t] += x;
    __syncthreads();
  }
  int excl = sh[t] - s + bbase[blockIdx.x];
#pragma unroll
  for (int j = 0; j < 4; ++j) {
    int idx = base + j;
    if (idx < n) {
      row_start[idx] = excl;
      cursor[idx] = excl;
    }
    excl += v[j];
  }
  if (blockIdx.x == gridDim.x - 1 && t == 255) row_start[n] = excl;  // == E
}

__global__ __launch_bounds__(256) void scatter_kernel(const int* __restrict__ src,
                                                      const int* __restrict__ dst, int E,
                                                      int* __restrict__ cursor,
                                                      int* __restrict__ csr_src) {
  int e = blockIdx.x * 256 + threadIdx.x;
  if (e < E) {
    int d = dst[e];
    int p = atomicAdd(&cursor[d], 1);
    csr_src[p] = src[e];
  }
}

// ---------------- weight conversion (both W's in one dispatch) --------------
// blocks 0..127: W1 [128][256] -> W1t [256][128] bf16 (plain transpose)
// blocks 128..255: W2 [256][128] -> W2t [128][256] bf16, K rows permuted to
//                  the physical layer-1 output layout.
__global__ __launch_bounds__(256) void conv_weights_kernel(const float* __restrict__ W1,
                                                           const float* __restrict__ W2,
                                                           unsigned short* __restrict__ W1t,
                                                           unsigned short* __restrict__ W2t) {
  int b = blockIdx.x;
  if (b < 128) {
    int idx = b * 256 + threadIdx.x;  // 32768
    int n = idx >> 7, k = idx & 127;
    W1t[idx] = f2bf(W1[k * 256 + n]);
  } else {
    int idx = (b - 128) * 256 + threadIdx.x;  // 32768
    int n = idx >> 8, p = idx & 255;
    int kl = (p & ~63) | ((p & 3) << 4) | ((p >> 2) & 15);
    W2t[idx] = f2bf(W2[kl * 128 + n]);
  }
}

// ---------------- persistent-B MFMA GEMM + fused attn-coeff epilogue --------
// C[M,NTOT] = A[M,K] @ B[K,NTOT]. Grid: (ceil(M/128), 2). Block: 256 thr.
// B panel (32KB) staged to LDS once; ALL A-frags loaded upfront (one latency
// exposure); K-loop fully unrolled over LDS B-frags.
// AF32: A is f32, converted to bf16 in-register after load.

template <int K, int NTOT, bool AF32>
__global__ __launch_bounds__(256) void gemm_mfma2(
    const void* __restrict__ Ap,            // [M][K] bf16 or f32
    const unsigned short* __restrict__ Bt,  // [NTOT][K] bf16 (pre-transposed)
    const float* __restrict__ a_s, const float* __restrict__ a_d,  // [NTOT] logical
    unsigned short* __restrict__ hout,      // [M][NTOT] bf16 physical layout
    float* __restrict__ als, float* __restrict__ ald,  // [M][4]
    int M) {
  constexpr int COLS = NTOT / 2;  // cols per block (128 / 64)
  constexpr int CFW = COLS / 16;  // col-frags per wave (8 / 4)
  constexpr int HLOG = NTOT / 4;  // logical cols per head (64 / 32)
  constexpr int CFH = HLOG / 16;  // col-frags per head (4 / 2)
  constexpr int VPT = NTOT / 64;  // phys pack width (4 / 2)
  constexpr int KS = K / 32;      // k-steps (4 / 8)
  __shared__ __align__(16) unsigned short Bs[COLS][K + 8];

  const int t = threadIdx.x;
  const int w = t >> 6;
  const int lane = t & 63;
  const int c16 = lane & 15;
  const int q = lane >> 4;
  const int gcol = blockIdx.y;
  const int bm = blockIdx.x * 128;

  // ---- stage B panel (COLS x K = 32 KB) once: 128 B (8x uint4) per thread --
  {
    constexpr int TPR = K / 64;  // threads per B row (2 / 4)
    int nloc = t / TPR;          // 0..COLS-1
    int part = (t % TPR) * 64;   // shorts offset
    const unsigned short* srcp = Bt + (size_t)(gcol * COLS + nloc) * K + part;
#pragma unroll
    for (int j = 0; j < 8; ++j) {
      uint4 v = *(const uint4*)(srcp + j * 8);  // 8 shorts = 16 B
      *(uint4*)&Bs[nloc][part + j * 8] = v;
    }
  }

  // ---- load ALL A-fragments upfront (2 rows x KS k-steps) ----
  int arow[2];
  arow[0] = min(bm + w * 32 + c16, M - 1);
  arow[1] = min(bm + w * 32 + 16 + c16, M - 1);
  short8 afr[2][KS];
  if constexpr (AF32) {
    float4 fv[2][KS][2];
#pragma unroll
    for (int rf = 0; rf < 2; ++rf) {
      const float* rp = (const float*)Ap + (size_t)arow[rf] * K;
#pragma unroll
      for (int ks = 0; ks < KS; ++ks) {
        fv[rf][ks][0] = *(const float4*)(rp + ks * 32 + q * 8);
        fv[rf][ks][1] = *(const float4*)(rp + ks * 32 + q * 8 + 4);
      }
    }
#pragma unroll
    for (int rf = 0; rf < 2; ++rf)
#pragma unroll
      for (int ks = 0; ks < KS; ++ks) {
        ushort4 u0, u1;
        u0.x = f2bf(fv[rf][ks][0].x); u0.y = f2bf(fv[rf][ks][0].y);
        u0.z = f2bf(fv[rf][ks][0].z); u0.w = f2bf(fv[rf][ks][0].w);
        u1.x = f2bf(fv[rf][ks][1].x); u1.y = f2bf(fv[rf][ks][1].y);
        u1.z = f2bf(fv[rf][ks][1].z); u1.w = f2bf(fv[rf][ks][1].w);
        union { ushort4 u[2]; short8 s; } cvt;
        cvt.u[0] = u0; cvt.u[1] = u1;
        afr[rf][ks] = cvt.s;
      }
  } else {
    const unsigned short* Ab = (const unsigned short*)Ap;
#pragma unroll
    for (int rf = 0; rf < 2; ++rf)
#pragma unroll
      for (int ks = 0; ks < KS; ++ks)
        afr[rf][ks] = *(const short8*)(Ab + (size_t)arow[rf] * K + ks * 32 + q * 8);
  }
  __syncthreads();

  float4v acc[2][CFW];
#pragma unroll
  for (int rf = 0; rf < 2; ++rf)
#pragma unroll
    for (int cf = 0; cf < CFW; ++cf) acc[rf][cf] = float4v{0.f, 0.f, 0.f, 0.f};

#pragma unroll
  for (int ks = 0; ks < KS; ++ks) {
#pragma unroll
    for (int cf = 0; cf < CFW; ++cf) {
      short8 bfrag = *(const short8*)&Bs[cf * 16 + c16][ks * 32 + q * 8];
#pragma unroll
      for (int rf = 0; rf < 2; ++rf)
        acc[rf][cf] =
            __builtin_amdgcn_mfma_f32_16x16x32_bf16(afr[rf][ks], bfrag, acc[rf][cf], 0, 0, 0);
    }
  }

  // ---- epilogue: phys-perm bf16 store + als/ald (2 heads per wave) ----
  float sasv[CFW], sadv[CFW];
#pragma unroll
  for (int cf = 0; cf < CFW; ++cf) {
    int L = gcol * COLS + cf * 16 + c16;
    sasv[cf] = a_s[L];
    sadv[cf] = a_d[L];
  }
#pragma unroll
  for (int rf = 0; rf < 2; ++rf) {
#pragma unroll
    for (int r = 0; r < 4; ++r) {
      int n = bm + w * 32 + rf * 16 + q * 4 + r;
      float ps[2] = {0.f, 0.f}, pd[2] = {0.f, 0.f};
      unsigned short us[CFW];
#pragma unroll
      for (int cf = 0; cf < CFW; ++cf) {
        float v = acc[rf][cf][r];
        us[cf] = f2bf(v);
        ps[cf / CFH] += v * sasv[cf];
        pd[cf / CFH] += v * sadv[cf];
      }
#pragma unroll
      for (int off = 1; off <= 8; off <<= 1) {
#pragma unroll
        for (int hl = 0; hl < 2; ++hl) {
          ps[hl] += __shfl_xor(ps[hl], off, 16);
          pd[hl] += __shfl_xor(pd[hl], off, 16);
        }
      }
      if (n < M) {
#pragma unroll
        for (int hl = 0; hl < 2; ++hl) {
          int head = gcol * 2 + hl;
          unsigned short* dst = hout + (size_t)n * NTOT + head * HLOG + c16 * VPT;
          if constexpr (VPT == 4) {
            ushort4 u;
            u.x = us[hl * 4 + 0]; u.y = us[hl * 4 + 1];
            u.z = us[hl * 4 + 2]; u.w = us[hl * 4 + 3];
            *(ushort4*)dst = u;
          } else {
            ushort2 u;
            u.x = us[hl * 2 + 0]; u.y = us[hl * 2 + 1];
            *(ushort2*)dst = u;
          }
          if (c16 == 0) {
            als[(size_t)n * 4 + head] = ps[hl];
            ald[(size_t)n * 4 + head] = pd[hl];
          }
        }
      }
    }
  }
}

// ---------------- GAT aggregation + bias + BN + ELU (+ fused layer-3 prep) --

template <int D, bool FUSEL3>
__global__ __launch_bounds__(256) void gat_aggregate(
    const unsigned short* __restrict__ h_bf, const float* __restrict__ als,
    const float* __restrict__ ald, const int* __restrict__ row_start,
    const int* __restrict__ csr_src, const float* __restrict__ bias,
    const float* __restrict__ gamma, const float* __restrict__ beta,
    const float* __restrict__ bmean, const float* __restrict__ bvar,
    unsigned short* __restrict__ obf,  // D==256 output
    const float* __restrict__ W3, const float* __restrict__ a3s,
    const float* __restrict__ a3d, float4* __restrict__ h3p,
    float* __restrict__ ald3,  // FUSEL3 outputs
    int n_nodes) {
  constexpr int VPT = D / WSZ;
  constexpr int H = 4;
  __shared__ float w3s[384];
  __shared__ float sa3[6];
  if constexpr (FUSEL3) {
    for (int i = threadIdx.x; i < 384; i += 256) w3s[i] = W3[i];
    if (threadIdx.x < 3) {
      sa3[threadIdx.x] = a3s[threadIdx.x];
      sa3[3 + threadIdx.x] = a3d[threadIdx.x];
    }
    __syncthreads();
  }
  int wid = threadIdx.x >> 6, lane = threadIdx.x & 63;
  int n = blockIdx.x * 4 + wid;
  if (n >= n_nodes) return;
  int c = lane * VPT;  // physical col base
  int hd = lane >> 4;  // head
  float aldv = ald[(size_t)n * H + hd];
  int row = row_start[n], end = row_start[n + 1];
  float acc[VPT] = {};
  float ssum = 0.f;
  int i = row;

#define EDGE_BLOCK(B)                                                          \
  for (; i + (B) - 1 < end; i += (B)) {                                        \
    int s[B];                                                                  \
    float e[B];                                                                \
    _Pragma("unroll") for (int j = 0; j < (B); ++j) s[j] = csr_src[i + j];     \
    _Pragma("unroll") for (int j = 0; j < (B); ++j) e[j] =                     \
        als[(size_t)s[j] * H + hd] + aldv;                                     \
    if constexpr (VPT == 4) {                                                  \
      uint2 u[B];                                                              \
      _Pragma("unroll") for (int j = 0; j < (B); ++j) u[j] =                   \
          *(const uint2*)(h_bf + (size_t)s[j] * D + c);                        \
      _Pragma("unroll") for (int j = 0; j < (B); ++j) {                        \
        float ee = e[j];                                                       \
        ee = (ee > 0.f) ? ee : 0.2f * ee;                                      \
        float ex = __expf(ee);                                                 \
        ssum += ex;                                                            \
        acc[0] += ex * __uint_as_float(u[j].x << 16);                          \
        acc[1] += ex * __uint_as_float(u[j].x & 0xFFFF0000u);                  \
        acc[2] += ex * __uint_as_float(u[j].y << 16);                          \
        acc[3] += ex * __uint_as_float(u[j].y & 0xFFFF0000u);                  \
      }                                                                        \
    } else {                                                                   \
      unsigned u[B];                                                           \
      _Pragma("unroll") for (int j = 0; j < (B); ++j) u[j] =                   \
          *(const unsigned*)(h_bf + (size_t)s[j] * D + c);                     \
      _Pragma("unroll") for (int j = 0; j < (B); ++j) {                        \
        float ee = e[j];                                                       \
        ee = (ee > 0.f) ? ee : 0.2f * ee;                                      \
        float ex = __expf(ee);                                                 \
        ssum += ex;                                                            \
        acc[0] += ex * __uint_as_float(u[j] << 16);                            \
        acc[1] += ex * __uint_as_float(u[j] & 0xFFFF0000u);                    \
      }                                                                        \
    }                                                                          \
  }

  EDGE_BLOCK(8)
  EDGE_BLOCK(4)
  EDGE_BLOCK(1)
#undef EDGE_BLOCK

  float inv = 1.f / (ssum + 1e-16f);
#pragma unroll
  for (int j = 0; j < VPT; ++j) {
    int cl = hd * (VPT * 16) + j * 16 + (lane & 15);  // logical col
    float o = acc[j] * inv + bias[cl];
    o = (o - bmean[cl]) * rsqrtf(bvar[cl] + 1e-5f) * gamma[cl] + beta[cl];
    o = (o > 0.f) ? o : (__expf(o) - 1.f);  // ELU
    acc[j] = o;
  }
  if constexpr (!FUSEL3) {
    ushort4 u;
    u.x = f2bf(acc[0]); u.y = f2bf(acc[1]); u.z = f2bf(acc[2]); u.w = f2bf(acc[3]);
    *(ushort4*)(obf + (size_t)n * D + c) = u;
  } else {
    // fused l3_prep: o2 row lives in acc[0..1] (phys cols c, c+1).
    int k0l = hd * 32 + (lane & 15);  // logical k of acc[0]
    int k1l = k0l + 16;               // logical k of acc[1]
    float p0 = acc[0] * w3s[k0l * 3 + 0] + acc[1] * w3s[k1l * 3 + 0];
    float p1 = acc[0] * w3s[k0l * 3 + 1] + acc[1] * w3s[k1l * 3 + 1];
    float p2 = acc[0] * w3s[k0l * 3 + 2] + acc[1] * w3s[k1l * 3 + 2];
#pragma unroll
    for (int off = 32; off >= 1; off >>= 1) {
      p0 += __shfl_xor(p0, off, 64);
      p1 += __shfl_xor(p1, off, 64);
      p2 += __shfl_xor(p2, off, 64);
    }
    if (lane == 0) {
      float als3 = p0 * sa3[0] + p1 * sa3[1] + p2 * sa3[2];
      float ad3 = p0 * sa3[3] + p1 * sa3[4] + p2 * sa3[5];
      h3p[n] = make_float4(p0, p1, p2, als3);
      ald3[n] = ad3;
    }
  }
}

// ---------------- layer 3 aggregation + log_softmax -------------------------

__global__ __launch_bounds__(256) void l3_agg_kernel(const float4* __restrict__ h3p,
                                                     const float* __restrict__ ald3,
                                                     const int* __restrict__ row_start,
                                                     const int* __restrict__ csr_src,
                                                     const float* __restrict__ b3,
                                                     float* __restrict__ out, int n_nodes) {
  int wid = threadIdx.x >> 6, lane = threadIdx.x & 63;
  int n = blockIdx.x * 4 + wid;
  if (n >= n_nodes) return;
  float aldv = ald3[n];
  int row = row_start[n], end = row_start[n + 1];
  float a0 = 0.f, a1 = 0.f, a2 = 0.f, ss = 0.f;
  for (int i = row + lane; i < end; i += 64) {
    int s = csr_src[i];
    float4 hv = h3p[s];
    float e = hv.w + aldv;
    e = (e > 0.f) ? e : 0.2f * e;
    float ex = __expf(e);
    ss += ex;
    a0 += ex * hv.x;
    a1 += ex * hv.y;
    a2 += ex * hv.z;
  }
#pragma unroll
  for (int off = 32; off >= 1; off >>= 1) {
    a0 += __shfl_xor(a0, off, 64);
    a1 += __shfl_xor(a1, off, 64);
    a2 += __shfl_xor(a2, off, 64);
    ss += __shfl_xor(ss, off, 64);
  }
  if (lane == 0) {
    float inv = 1.f / (ss + 1e-16f);
    float o0 = a0 * inv + b3[0];
    float o1 = a1 * inv + b3[1];
    float o2 = a2 * inv + b3[2];
    float m = fmaxf(o0, fmaxf(o1, o2));
    float lse = m + logf(expf(o0 - m) + expf(o1 - m) + expf(o2 - m));
    out[n * 3 + 0] = o0 - lse;
    out[n * 3 + 1] = o1 - lse;
    out[n * 3 + 2] = o2 - lse;
  }
}

// ---------------------------------------------------------------------------

extern "C" void kernel_launch(void* const* d_in, const int* in_sizes, int n_in,
                              void* d_out, int out_size, void* d_ws, size_t ws_size,
                              hipStream_t stream) {
  const float* x   = (const float*)d_in[0];
  const int*   ei  = (const int*)d_in[1];
  const float* W1  = (const float*)d_in[2];
  const float* a1s = (const float*)d_in[3];
  const float* a1d = (const float*)d_in[4];
  const float* b1  = (const float*)d_in[5];
  const float* g1v = (const float*)d_in[6];
  const float* be1 = (const float*)d_in[7];
  const float* m1  = (const float*)d_in[8];
  const float* v1  = (const float*)d_in[9];
  const float* W2  = (const float*)d_in[10];
  const float* a2s = (const float*)d_in[11];
  const float* a2d = (const float*)d_in[12];
  const float* b2  = (const float*)d_in[13];
  const float* g2v = (const float*)d_in[14];
  const float* be2 = (const float*)d_in[15];
  const float* m2  = (const float*)d_in[16];
  const float* v2  = (const float*)d_in[17];
  const float* W3  = (const float*)d_in[18];
  const float* a3s = (const float*)d_in[19];
  const float* a3d = (const float*)d_in[20];
  const float* b3  = (const float*)d_in[21];
  float* out = (float*)d_out;

  const int N = in_sizes[0] / 128;  // 50000
  const int E = in_sizes[1] / 2;    // 850000
  const int* srcv = ei;
  const int* dstv = ei + E;

  // workspace carve-up (~77 MB)
  float* wsf  = (float*)d_ws;
  float* als1 = wsf;                  // N*4
  float* ald1 = als1 + (size_t)N * 4;
  float* als2 = ald1 + (size_t)N * 4;
  float* ald2 = als2 + (size_t)N * 4;
  float* h3p  = ald2 + (size_t)N * 4;  // N*4 (float4 rows)
  float* ald3 = h3p + (size_t)N * 4;   // N
  unsigned short* h_bf1 = (unsigned short*)(ald3 + N);  // N*256
  unsigned short* o1_bf = h_bf1 + (size_t)N * 256;      // N*256
  unsigned short* h_bf2 = o1_bf + (size_t)N * 256;      // N*128
  unsigned short* W1t   = h_bf2 + (size_t)N * 128;      // 256*128
  unsigned short* W2t   = W1t + 256 * 128;              // 128*256
  int* deg       = (int*)(W2t + 128 * 256);  // N
  int* row_start = deg + N;                  // N+1
  int* cursor    = row_start + (N + 1);      // N+1
  int* csr_src   = cursor + (N + 1);         // E
  int* bsum      = csr_src + E;              // 1024

  const int eb = (E + 255) / 256;
  const int nb = (N + 1023) / 1024;
  const int nodes4 = (N + 3) / 4;
  const dim3 gemm_grid((N + 127) / 128, 2);

  // weight conversions (one dispatch)
  conv_weights_kernel<<<256, 256, 0, stream>>>(W1, W2, W1t, W2t);

  // CSR build (shared by all 3 layers)
  hipMemsetAsync(deg, 0, (size_t)N * sizeof(int), stream);
  hist_kernel<<<eb, 256, 0, stream>>>(dstv, E, deg);
  block_sums_kernel<<<nb, 256, 0, stream>>>(deg, N, bsum);
  scan_blocks_kernel<<<1, 64, 0, stream>>>(bsum, nb);
  scan_write_kernel<<<nb, 256, 0, stream>>>(deg, N, bsum, row_start, cursor);
  scatter_kernel<<<eb, 256, 0, stream>>>(srcv, dstv, E, cursor, csr_src);

  // layer 1 (A = f32 x, converted in-register)
  gemm_mfma2<128, 256, true><<<gemm_grid, 256, 0, stream>>>(x, W1t, a1s, a1d, h_bf1, als1,
                                                            ald1, N);
  gat_aggregate<256, false><<<nodes4, 256, 0, stream>>>(
      h_bf1, als1, ald1, row_start, csr_src, b1, g1v, be1, m1, v1, o1_bf, nullptr, nullptr,
      nullptr, nullptr, nullptr, N);
  // layer 2
  gemm_mfma2<256, 128, false><<<gemm_grid, 256, 0, stream>>>(o1_bf, W2t, a2s, a2d, h_bf2,
                                                             als2, ald2, N);
  gat_aggregate<128, true><<<nodes4, 256, 0, stream>>>(
      h_bf2, als2, ald2, row_start, csr_src, b2, g2v, be2, m2, v2, nullptr, W3, a3s, a3d,
      (float4*)h3p, ald3, N);
  // layer 3 + log_softmax
  l3_agg_kernel<<<nodes4, 256, 0, stream>>>((const float4*)h3p, ald3, row_start, csr_src,
                                            b3, out, N);
}